// Round 1
// baseline (324.859 us; speedup 1.0000x reference)
//
#include <hip/hip_runtime.h>
#include <hip/hip_bf16.h>

#define NWAVE 16

constexpr float PI_OVER_CUT = 3.14159265358979323846f / 5.0f;

// ---------------- counting sort: histogram -> scan -> scatter ----------------

__global__ void hist_kernel(const int* __restrict__ idx0, unsigned* __restrict__ counts, int nneigh) {
    int j = blockIdx.x * blockDim.x + threadIdx.x;
    if (j < nneigh) atomicAdd(&counts[idx0[j]], 1u);
}

__global__ void scan_kernel(const unsigned* __restrict__ counts, unsigned* __restrict__ offsets,
                            unsigned* __restrict__ cursor, int nlocal) {
    __shared__ unsigned part[1024];
    int t = threadIdx.x;
    int ch = (nlocal + 1023) / 1024;
    int base = t * ch;
    unsigned s = 0;
    for (int i = 0; i < ch; ++i) { int id = base + i; if (id < nlocal) s += counts[id]; }
    part[t] = s;
    __syncthreads();
    for (int off = 1; off < 1024; off <<= 1) {
        unsigned v = (t >= off) ? part[t - off] : 0u;
        __syncthreads();
        part[t] += v;
        __syncthreads();
    }
    unsigned run = (t == 0) ? 0u : part[t - 1];
    for (int i = 0; i < ch; ++i) {
        int id = base + i;
        if (id < nlocal) { offsets[id] = run; cursor[id] = run; run += counts[id]; }
    }
    if (t == 1023) offsets[nlocal] = part[1023];
}

__global__ void scatter_kernel(const int* __restrict__ idx0, unsigned* __restrict__ cursor,
                               unsigned* __restrict__ sorted, int nneigh) {
    int j = blockIdx.x * blockDim.x + threadIdx.x;
    if (j < nneigh) {
        unsigned p = atomicAdd(&cursor[idx0[j]], 1u);
        sorted[p] = (unsigned)j;
    }
}

// ---------------- main: one wave per local atom ----------------
// lane = g*16 + k.  k owns wave channel (radial index), g owns angular comps:
//   g=0: comps {0,4,8,12}  = fcut*{1, dx*dx, dy*dy, dz*dz}
//   g=1: comps {1,5,9}     = fcut*{dx, dx*dy, dy*dz}
//   g=2: comps {2,6,10}    = fcut*{dy, dx*dz, dz*dx}
//   g=3: comps {3,7,11}    = fcut*{dz, dy*dx, dz*dy}
// density[0][k]=sumw(c0)^2; [1][k]=sum c1..3; [2][k]=sum c4..12.

__global__ __launch_bounds__(256) void density_kernel(
    const float* __restrict__ cart, const float* __restrict__ rs,
    const float* __restrict__ inta, const float* __restrict__ params,
    const int* __restrict__ idx1, const int* __restrict__ nspec,
    const unsigned* __restrict__ offsets, const unsigned* __restrict__ sorted,
    float* __restrict__ out, int nlocal)
{
    int lane = threadIdx.x & 63;
    int a = blockIdx.x * 4 + (threadIdx.x >> 6);
    if (a >= nlocal) return;
    int k = lane & 15;
    int g = lane >> 4;

    float c0x = cart[3*a], c0y = cart[3*a+1], c0z = cart[3*a+2];

    int a1, b1, a2, b2;
    switch (g) {
      case 0:  a1=0; b1=0; a2=1; b2=1; break;   // comp4 (0,0), comp8 (1,1)
      case 1:  a1=0; b1=1; a2=1; b2=2; break;   // comp5 (0,1), comp9 (1,2)
      case 2:  a1=0; b1=2; a2=2; b2=0; break;   // comp6 (0,2), comp10 (2,0)
      default: a1=1; b1=0; a2=2; b2=1; break;   // comp7 (1,0), comp11 (2,1)
    }

    float acc0 = 0.f, acc1 = 0.f, acc2 = 0.f, acc3 = 0.f;
    unsigned beg = offsets[a], end = offsets[a + 1];
    for (unsigned n = beg; n < end; ++n) {
        int j  = (int)sorted[n];          // uniform per wave -> broadcast load
        int i1 = idx1[j];
        int s  = nspec[j];
        float dxv = c0x - cart[3*i1];
        float dyv = c0y - cart[3*i1+1];
        float dzv = c0z - cart[3*i1+2];
        float d2   = dxv*dxv + dyv*dyv + dzv*dzv;
        float rinv = rsqrtf(d2);
        float dist = d2 * rinv;
        float dx = dxv * rinv, dy = dyv * rinv, dz = dzv * rinv;
        float fc   = 0.5f * __cosf(dist * PI_OVER_CUT) + 0.5f;
        float fcut = fc * fc;
        float t    = dist - rs[s*NWAVE + k];
        float rad  = __expf(-inta[s*NWAVE + k] * t * t) * params[s*NWAVE + k];

        float f1 = (g == 0) ? fcut : fcut * (g == 1 ? dx : (g == 2 ? dy : dz));
        acc0 = fmaf(f1, rad, acc0);
        float pa1 = (a1 == 0 ? dx : (a1 == 1 ? dy : dz));
        float pb1 = (b1 == 0 ? dx : (b1 == 1 ? dy : dz));
        acc1 = fmaf(fcut * pa1 * pb1, rad, acc1);
        float pa2 = (a2 == 0 ? dx : (a2 == 1 ? dy : dz));
        float pb2 = (b2 == 0 ? dx : (b2 == 1 ? dy : dz));
        acc2 = fmaf(fcut * pa2 * pb2, rad, acc2);
        if (g == 0) acc3 = fmaf(fcut * dz * dz, rad, acc3);
    }

    float l0, l1, l2;
    if (g == 0) { l0 = acc0*acc0; l1 = 0.f;        l2 = acc1*acc1 + acc2*acc2 + acc3*acc3; }
    else        { l0 = 0.f;       l1 = acc0*acc0;  l2 = acc1*acc1 + acc2*acc2; }
    l0 += __shfl_xor(l0, 16, 64); l1 += __shfl_xor(l1, 16, 64); l2 += __shfl_xor(l2, 16, 64);
    l0 += __shfl_xor(l0, 32, 64); l1 += __shfl_xor(l1, 32, 64); l2 += __shfl_xor(l2, 32, 64);

    if (g == 0) {
        out[a*48 + k]      = l0;
        out[a*48 + 16 + k] = l1;
        out[a*48 + 32 + k] = l2;
    }
}

extern "C" void kernel_launch(void* const* d_in, const int* in_sizes, int n_in,
                              void* d_out, int out_size, void* d_ws, size_t ws_size,
                              hipStream_t stream) {
    const float* cart   = (const float*)d_in[0];
    const float* rs     = (const float*)d_in[1];
    const float* inta   = (const float*)d_in[2];
    const float* params = (const float*)d_in[3];
    const int* atom_index    = (const int*)d_in[4];
    const int* neigh_species = (const int*)d_in[6];
    int nlocal = in_sizes[5];
    int nneigh = in_sizes[6];
    const int* idx0 = atom_index;
    const int* idx1 = atom_index + nneigh;

    unsigned* counts  = (unsigned*)d_ws;             // nlocal
    unsigned* offsets = counts + nlocal;             // nlocal + 1
    unsigned* cursor  = offsets + nlocal + 1;        // nlocal
    unsigned* sorted  = cursor + nlocal;             // nneigh

    hipMemsetAsync(counts, 0, (size_t)nlocal * sizeof(unsigned), stream);

    int tb = 256;
    hist_kernel<<<(nneigh + tb - 1) / tb, tb, 0, stream>>>(idx0, counts, nneigh);
    scan_kernel<<<1, 1024, 0, stream>>>(counts, offsets, cursor, nlocal);
    scatter_kernel<<<(nneigh + tb - 1) / tb, tb, 0, stream>>>(idx0, cursor, sorted, nneigh);

    int nblocks = (nlocal + 3) / 4;
    density_kernel<<<nblocks, 256, 0, stream>>>(cart, rs, inta, params, idx1, neigh_species,
                                                offsets, sorted, (float*)d_out, nlocal);
}

// Round 2
// 181.141 us; speedup vs baseline: 1.7934x; 1.7934x over previous
//
#include <hip/hip_runtime.h>
#include <hip/hip_bf16.h>

#define NWAVE 16

constexpr float PI_OVER_CUT = 3.14159265358979323846f / 5.0f;

// ======================= histogram =======================

__global__ void hist_kernel(const int* __restrict__ idx0, unsigned* __restrict__ counts, int nneigh) {
    int j = blockIdx.x * blockDim.x + threadIdx.x;
    if (j < nneigh) atomicAdd(&counts[idx0[j]], 1u);
}

// ======================= 3-stage parallel exclusive scan =======================
// stage 1: per-block (1024 elems) sums -> partials[bid]
__global__ __launch_bounds__(256) void scan_partial(const unsigned* __restrict__ counts,
                                                    unsigned* __restrict__ partials, int n) {
    __shared__ unsigned wsum[4];
    int t = threadIdx.x;
    int base = blockIdx.x * 1024 + t * 4;
    unsigned s = 0;
    #pragma unroll
    for (int e = 0; e < 4; ++e) { int id = base + e; if (id < n) s += counts[id]; }
    #pragma unroll
    for (int off = 32; off >= 1; off >>= 1) s += __shfl_xor(s, off, 64);
    int lane = t & 63, w = t >> 6;
    if (lane == 0) wsum[w] = s;
    __syncthreads();
    if (t == 0) partials[blockIdx.x] = wsum[0] + wsum[1] + wsum[2] + wsum[3];
}

// stage 2: one wave scans the (<=64) block partials -> exclusive blockoff; writes total
__global__ __launch_bounds__(64) void scan_blockoffs(const unsigned* __restrict__ partials,
                                                     unsigned* __restrict__ blockoff,
                                                     unsigned* __restrict__ offsets,
                                                     int nblk, int nlocal) {
    int t = threadIdx.x;
    unsigned v = (t < nblk) ? partials[t] : 0u;
    unsigned incl = v;
    #pragma unroll
    for (int off = 1; off < 64; off <<= 1) {
        unsigned u = __shfl_up(incl, off, 64);
        if (t >= off) incl += u;
    }
    if (t < nblk) blockoff[t] = incl - v;
    if (t == nblk - 1) offsets[nlocal] = incl;
}

// stage 3: per-block exclusive scan + blockoff -> offsets & cursor
__global__ __launch_bounds__(256) void scan_final(const unsigned* __restrict__ counts,
                                                  const unsigned* __restrict__ blockoff,
                                                  unsigned* __restrict__ offsets,
                                                  unsigned* __restrict__ cursor, int n) {
    __shared__ unsigned wsum[4];
    int t = threadIdx.x;
    int lane = t & 63, w = t >> 6;
    int base = blockIdx.x * 1024 + t * 4;
    unsigned c[4];
    #pragma unroll
    for (int e = 0; e < 4; ++e) { int id = base + e; c[e] = (id < n) ? counts[id] : 0u; }
    unsigned tsum = c[0] + c[1] + c[2] + c[3];
    unsigned incl = tsum;
    #pragma unroll
    for (int off = 1; off < 64; off <<= 1) {
        unsigned u = __shfl_up(incl, off, 64);
        if (lane >= off) incl += u;
    }
    if (lane == 63) wsum[w] = incl;
    __syncthreads();
    unsigned wpre = 0;
    for (int i = 0; i < 4; ++i) if (i < w) wpre += wsum[i];
    unsigned x = blockoff[blockIdx.x] + wpre + (incl - tsum);
    #pragma unroll
    for (int e = 0; e < 4; ++e) {
        int id = base + e;
        if (id < n) { offsets[id] = x; cursor[id] = x; }
        x += c[e];
    }
}

// ======================= geometry + permutation scatter =======================
// One thread per neighbor: compute dx,dy,dz,dist,fcut once, write at permuted slot.

__global__ __launch_bounds__(256) void geom_scatter(
    const float* __restrict__ cart, const int* __restrict__ idx0,
    const int* __restrict__ idx1, const int* __restrict__ nspec,
    unsigned* __restrict__ cursor, float4* __restrict__ geomA,
    float2* __restrict__ geomB, int nneigh)
{
    int j = blockIdx.x * blockDim.x + threadIdx.x;
    if (j >= nneigh) return;
    int i0 = idx0[j], i1 = idx1[j], s = nspec[j];
    float ax = cart[3*i0], ay = cart[3*i0+1], az = cart[3*i0+2];
    float bx = cart[3*i1], by = cart[3*i1+1], bz = cart[3*i1+2];
    float dxv = ax - bx, dyv = ay - by, dzv = az - bz;
    float d2 = dxv*dxv + dyv*dyv + dzv*dzv;
    float rinv = rsqrtf(d2);
    float dist = d2 * rinv;
    float fc = 0.5f * __cosf(dist * PI_OVER_CUT) + 0.5f;
    float fcut = fc * fc;
    unsigned p = atomicAdd(&cursor[i0], 1u);
    geomA[p] = make_float4(dxv * rinv, dyv * rinv, dzv * rinv, dist);
    geomB[p] = make_float2(fcut, __int_as_float(s));
}

// ======================= density: one wave per local atom =======================
// lane = g*16 + k.  k = wave channel, g picks angular comps (see R1 comments).

__global__ __launch_bounds__(256) void density_fast(
    const float* __restrict__ rs, const float* __restrict__ inta,
    const float* __restrict__ params, const unsigned* __restrict__ offsets,
    const float4* __restrict__ geomA, const float2* __restrict__ geomB,
    float* __restrict__ out, int nlocal)
{
    __shared__ float4 tab[64];   // [s][k] = {rs, inta, params, 0}
    int t = threadIdx.x;
    if (t < 64) {
        int s = t >> 4, k = t & 15;
        tab[t] = make_float4(rs[s*NWAVE + k], inta[s*NWAVE + k], params[s*NWAVE + k], 0.f);
    }
    __syncthreads();

    int a = blockIdx.x * 4 + (t >> 6);
    if (a >= nlocal) return;
    int lane = t & 63;
    int k = lane & 15, g = lane >> 4;

    int a1, b1, a2, b2;
    switch (g) {
      case 0:  a1=0; b1=0; a2=1; b2=1; break;   // xx, yy (+zz in acc3)
      case 1:  a1=0; b1=1; a2=1; b2=2; break;   // xy, yz
      case 2:  a1=0; b1=2; a2=2; b2=0; break;   // xz, zx
      default: a1=1; b1=0; a2=2; b2=1; break;   // yx, zy
    }

    float acc0 = 0.f, acc1 = 0.f, acc2 = 0.f, acc3 = 0.f;
    unsigned beg = offsets[a], end = offsets[a + 1];
    for (unsigned n = beg; n < end; ++n) {
        float4 gA = geomA[n];                 // dx,dy,dz,dist (broadcast, affine addr)
        float2 gB = geomB[n];                 // fcut, species bits
        int s = __float_as_int(gB.y);
        float4 tb = tab[s*NWAVE + k];         // one ds_read_b128, 2-way conflict (free)
        float dd = gA.w - tb.x;
        float rad = __expf(-tb.y * dd * dd) * (gB.x * tb.z);
        float dx = gA.x, dy = gA.y, dz = gA.z;

        float f1 = (g == 0) ? 1.f : (g == 1 ? dx : (g == 2 ? dy : dz));
        acc0 = fmaf(f1, rad, acc0);
        float pa1 = (a1 == 0 ? dx : (a1 == 1 ? dy : dz));
        float pb1 = (b1 == 0 ? dx : (b1 == 1 ? dy : dz));
        acc1 = fmaf(pa1 * pb1, rad, acc1);
        float pa2 = (a2 == 0 ? dx : (a2 == 1 ? dy : dz));
        float pb2 = (b2 == 0 ? dx : (b2 == 1 ? dy : dz));
        acc2 = fmaf(pa2 * pb2, rad, acc2);
        if (g == 0) acc3 = fmaf(dz * dz, rad, acc3);
    }

    float l0, l1, l2;
    if (g == 0) { l0 = acc0*acc0; l1 = 0.f;       l2 = acc1*acc1 + acc2*acc2 + acc3*acc3; }
    else        { l0 = 0.f;       l1 = acc0*acc0; l2 = acc1*acc1 + acc2*acc2; }
    l0 += __shfl_xor(l0, 16, 64); l1 += __shfl_xor(l1, 16, 64); l2 += __shfl_xor(l2, 16, 64);
    l0 += __shfl_xor(l0, 32, 64); l1 += __shfl_xor(l1, 32, 64); l2 += __shfl_xor(l2, 32, 64);

    if (g == 0) {
        out[a*48 + k]      = l0;
        out[a*48 + 16 + k] = l1;
        out[a*48 + 32 + k] = l2;
    }
}

// ======================= fallback (R1 path, small workspace) =======================

__global__ void scan_kernel_1blk(const unsigned* __restrict__ counts, unsigned* __restrict__ offsets,
                                 unsigned* __restrict__ cursor, int nlocal) {
    __shared__ unsigned part[1024];
    int t = threadIdx.x;
    int ch = (nlocal + 1023) / 1024;
    int base = t * ch;
    unsigned s = 0;
    for (int i = 0; i < ch; ++i) { int id = base + i; if (id < nlocal) s += counts[id]; }
    part[t] = s;
    __syncthreads();
    for (int off = 1; off < 1024; off <<= 1) {
        unsigned v = (t >= off) ? part[t - off] : 0u;
        __syncthreads();
        part[t] += v;
        __syncthreads();
    }
    unsigned run = (t == 0) ? 0u : part[t - 1];
    for (int i = 0; i < ch; ++i) {
        int id = base + i;
        if (id < nlocal) { offsets[id] = run; cursor[id] = run; run += counts[id]; }
    }
    if (t == 1023) offsets[nlocal] = part[1023];
}

__global__ void scatter_kernel(const int* __restrict__ idx0, unsigned* __restrict__ cursor,
                               unsigned* __restrict__ sorted, int nneigh) {
    int j = blockIdx.x * blockDim.x + threadIdx.x;
    if (j < nneigh) {
        unsigned p = atomicAdd(&cursor[idx0[j]], 1u);
        sorted[p] = (unsigned)j;
    }
}

__global__ __launch_bounds__(256) void density_kernel(
    const float* __restrict__ cart, const float* __restrict__ rs,
    const float* __restrict__ inta, const float* __restrict__ params,
    const int* __restrict__ idx1, const int* __restrict__ nspec,
    const unsigned* __restrict__ offsets, const unsigned* __restrict__ sorted,
    float* __restrict__ out, int nlocal)
{
    int lane = threadIdx.x & 63;
    int a = blockIdx.x * 4 + (threadIdx.x >> 6);
    if (a >= nlocal) return;
    int k = lane & 15;
    int g = lane >> 4;
    float c0x = cart[3*a], c0y = cart[3*a+1], c0z = cart[3*a+2];
    int a1, b1, a2, b2;
    switch (g) {
      case 0:  a1=0; b1=0; a2=1; b2=1; break;
      case 1:  a1=0; b1=1; a2=1; b2=2; break;
      case 2:  a1=0; b1=2; a2=2; b2=0; break;
      default: a1=1; b1=0; a2=2; b2=1; break;
    }
    float acc0 = 0.f, acc1 = 0.f, acc2 = 0.f, acc3 = 0.f;
    unsigned beg = offsets[a], end = offsets[a + 1];
    for (unsigned n = beg; n < end; ++n) {
        int j  = (int)sorted[n];
        int i1 = idx1[j];
        int s  = nspec[j];
        float dxv = c0x - cart[3*i1];
        float dyv = c0y - cart[3*i1+1];
        float dzv = c0z - cart[3*i1+2];
        float d2   = dxv*dxv + dyv*dyv + dzv*dzv;
        float rinv = rsqrtf(d2);
        float dist = d2 * rinv;
        float dx = dxv * rinv, dy = dyv * rinv, dz = dzv * rinv;
        float fc   = 0.5f * __cosf(dist * PI_OVER_CUT) + 0.5f;
        float fcut = fc * fc;
        float tt   = dist - rs[s*NWAVE + k];
        float rad  = __expf(-inta[s*NWAVE + k] * tt * tt) * params[s*NWAVE + k];
        float f1 = (g == 0) ? fcut : fcut * (g == 1 ? dx : (g == 2 ? dy : dz));
        acc0 = fmaf(f1, rad, acc0);
        float pa1 = (a1 == 0 ? dx : (a1 == 1 ? dy : dz));
        float pb1 = (b1 == 0 ? dx : (b1 == 1 ? dy : dz));
        acc1 = fmaf(fcut * pa1 * pb1, rad, acc1);
        float pa2 = (a2 == 0 ? dx : (a2 == 1 ? dy : dz));
        float pb2 = (b2 == 0 ? dx : (b2 == 1 ? dy : dz));
        acc2 = fmaf(fcut * pa2 * pb2, rad, acc2);
        if (g == 0) acc3 = fmaf(fcut * dz * dz, rad, acc3);
    }
    float l0, l1, l2;
    if (g == 0) { l0 = acc0*acc0; l1 = 0.f;        l2 = acc1*acc1 + acc2*acc2 + acc3*acc3; }
    else        { l0 = 0.f;       l1 = acc0*acc0;  l2 = acc1*acc1 + acc2*acc2; }
    l0 += __shfl_xor(l0, 16, 64); l1 += __shfl_xor(l1, 16, 64); l2 += __shfl_xor(l2, 16, 64);
    l0 += __shfl_xor(l0, 32, 64); l1 += __shfl_xor(l1, 32, 64); l2 += __shfl_xor(l2, 32, 64);
    if (g == 0) {
        out[a*48 + k]      = l0;
        out[a*48 + 16 + k] = l1;
        out[a*48 + 32 + k] = l2;
    }
}

// ======================= launch =======================

extern "C" void kernel_launch(void* const* d_in, const int* in_sizes, int n_in,
                              void* d_out, int out_size, void* d_ws, size_t ws_size,
                              hipStream_t stream) {
    const float* cart   = (const float*)d_in[0];
    const float* rs     = (const float*)d_in[1];
    const float* inta   = (const float*)d_in[2];
    const float* params = (const float*)d_in[3];
    const int* atom_index    = (const int*)d_in[4];
    const int* neigh_species = (const int*)d_in[6];
    int nlocal = in_sizes[5];
    int nneigh = in_sizes[6];
    const int* idx0 = atom_index;
    const int* idx1 = atom_index + nneigh;

    char* ws = (char*)d_ws;
    size_t off = 0;
    auto carve = [&](size_t bytes) -> char* {
        off = (off + 255) & ~(size_t)255;
        char* p = ws + off;
        off += bytes;
        return p;
    };
    unsigned* counts   = (unsigned*)carve((size_t)nlocal * 4);
    unsigned* offsets  = (unsigned*)carve(((size_t)nlocal + 1) * 4);
    unsigned* cursor   = (unsigned*)carve((size_t)nlocal * 4);
    unsigned* partials = (unsigned*)carve(256 * 4);
    unsigned* blockoff = (unsigned*)carve(256 * 4);
    float4*   geomA    = (float4*)carve((size_t)nneigh * 16);
    float2*   geomB    = (float2*)carve((size_t)nneigh * 8);
    size_t need_fast = (off + 255) & ~(size_t)255;

    int tb = 256;
    int nblkN = (nneigh + tb - 1) / tb;
    int nblkS = (nlocal + 1023) / 1024;   // 1024 counts per scan block

    hipMemsetAsync(counts, 0, (size_t)nlocal * 4, stream);
    hist_kernel<<<nblkN, tb, 0, stream>>>(idx0, counts, nneigh);

    if (ws_size >= need_fast && nblkS <= 64) {
        scan_partial<<<nblkS, 256, 0, stream>>>(counts, partials, nlocal);
        scan_blockoffs<<<1, 64, 0, stream>>>(partials, blockoff, offsets, nblkS, nlocal);
        scan_final<<<nblkS, 256, 0, stream>>>(counts, blockoff, offsets, cursor, nlocal);
        geom_scatter<<<nblkN, tb, 0, stream>>>(cart, idx0, idx1, neigh_species,
                                               cursor, geomA, geomB, nneigh);
        density_fast<<<(nlocal + 3) / 4, 256, 0, stream>>>(rs, inta, params, offsets,
                                                           geomA, geomB, (float*)d_out, nlocal);
    } else {
        unsigned* sorted = (unsigned*)geomA;  // reuse region
        scan_kernel_1blk<<<1, 1024, 0, stream>>>(counts, offsets, cursor, nlocal);
        scatter_kernel<<<nblkN, tb, 0, stream>>>(idx0, cursor, sorted, nneigh);
        density_kernel<<<(nlocal + 3) / 4, 256, 0, stream>>>(cart, rs, inta, params, idx1,
                                                             neigh_species, offsets, sorted,
                                                             (float*)d_out, nlocal);
    }
}